// Round 1
// baseline (106.604 us; speedup 1.0000x reference)
//
#include <hip/hip_runtime.h>

#define B 32
#define M 32
#define H 128
#define EPS 1e-6f

// ---------------- workspace layout (floats) ----------------
// metric : B*M*M  = 32768   @ 0        (symmetrized metric)
// mj     : B*M*256= 262144  @ 32768    (metric[b,x] @ Wr1[64:96])
// S      : B*256  = 8192    @ 294912   (sum over pairs of relu(h1))
// total 303104 floats = 1.19 MB

// Kernel 1: metric = sym(relu(points@Wm1+bm1)@Wm2+bm2 + eps*I); zero S.
__global__ __launch_bounds__(256) void k_metric(
    const float* __restrict__ points, const float* __restrict__ Wm1,
    const float* __restrict__ bm1, const float* __restrict__ Wm2,
    const float* __restrict__ bm2, float* __restrict__ metric,
    float* __restrict__ S)
{
    const int b = blockIdx.x, t = threadIdx.x;
    __shared__ float p[M];
    __shared__ float h[H];
    __shared__ float comps[M * M];
    if (t < M) p[t] = points[b * M + t];
    __syncthreads();
    if (t < H) {
        float acc = bm1[t];
        #pragma unroll
        for (int m = 0; m < M; ++m) acc = fmaf(p[m], Wm1[m * H + t], acc);
        h[t] = fmaxf(acc, 0.f);
    }
    __syncthreads();
    #pragma unroll
    for (int r = 0; r < 4; ++r) {
        const int d = t + 256 * r;
        float acc = bm2[d];
        for (int u = 0; u < H; ++u) acc = fmaf(h[u], Wm2[u * (M * M) + d], acc);
        comps[d] = acc;
    }
    __syncthreads();
    #pragma unroll
    for (int r = 0; r < 4; ++r) {
        const int d = t + 256 * r;
        const int ii = d >> 5, jj = d & 31;
        metric[b * M * M + d] =
            0.5f * (comps[ii * M + jj] + comps[jj * M + ii]) + (ii == jj ? EPS : 0.f);
    }
    S[b * 256 + t] = 0.f;
}

// Kernel 2: mj[b,x,:] = metric[b,x,:] @ Wr1[64:96, :]
__global__ __launch_bounds__(256) void k_mj(
    const float* __restrict__ metric, const float* __restrict__ Wr1,
    float* __restrict__ mj)
{
    const int bi = blockIdx.x;   // b*M + x
    const int t = threadIdx.x;
    __shared__ float row[M];
    if (t < M) row[t] = metric[bi * M + t];
    __syncthreads();
    float a = 0.f;
    #pragma unroll
    for (int m = 0; m < M; ++m) a = fmaf(row[m], Wr1[(64 + m) * 256 + t], a);
    mj[bi * 256 + t] = a;
}

// Kernel 3 (dominant): per block (b,i): for all j,k: christoffel MLP +
// ricci first layer + relu + reduce-sum into S[b].
__global__ __launch_bounds__(256) void k_main(
    const float* __restrict__ points, const float* __restrict__ metric,
    const float* __restrict__ Wc1, const float* __restrict__ bc1,
    const float* __restrict__ Wc2, const float* __restrict__ bc2,
    const float* __restrict__ Wr1, const float* __restrict__ br1,
    const float* __restrict__ mj, float* __restrict__ S)
{
    const int blk = blockIdx.x;
    const int b = blk >> 5, i = blk & 31;
    const int t = threadIdx.x;

    __shared__ float plds[M];
    __shared__ float mlds[M * M];      // metric[b] (symmetric)
    __shared__ float wr1c[M * 256];    // Wr1[96:128] — 32 KB
    __shared__ float bmi[256];         // points@Wr1[0:32] + br1 + row_i@Wr1[32:64]
    __shared__ float Slds[256];

    if (t < M) plds[t] = points[b * M + t];
    for (int d = t; d < M * M; d += 256) mlds[d] = metric[b * M * M + d];
    for (int d = t; d < M * 256; d += 256) wr1c[d] = Wr1[96 * 256 + d];
    Slds[t] = 0.f;
    __syncthreads();
    {
        float acc = br1[t];
        #pragma unroll
        for (int m = 0; m < M; ++m) acc = fmaf(plds[m], Wr1[m * 256 + t], acc);
        #pragma unroll
        for (int m = 0; m < M; ++m) acc = fmaf(mlds[i * M + m], Wr1[(32 + m) * 256 + t], acc);
        bmi[t] = acc;
    }
    __syncthreads();

    const int w = t >> 6;      // wave id: handles j in [8w, 8w+8)
    const int l = t & 63;
    const int k = l & 31;      // christoffel k index
    const int ph = l >> 5;     // which of the 2 concurrent pairs

    const float g_ki = mlds[i * M + k];   // metric[k][i] == metric[i][k] (symmetric)
    const float bc2v = bc2[0];

    float sacc0 = 0.f, sacc1 = 0.f, sacc2 = 0.f, sacc3 = 0.f;

    for (int jq = 0; jq < 4; ++jq) {
        const int j0 = w * 8 + jq * 2;
        const int jp = j0 + ph;
        const float g_ij = mlds[i * M + jp];
        const float g_jk = mlds[jp * M + k];

        // christoffel MLP for (b,i,jp,k): weights are wave-uniform -> s_load
        float hsum = 0.f;
        #pragma unroll 8
        for (int u = 0; u < H; ++u) {
            float pre = fmaf(g_ij, Wc1[u],
                        fmaf(g_jk, Wc1[H + u],
                        fmaf(g_ki, Wc1[2 * H + u], bc1[u])));
            float e = __expf(pre + pre);                              // e^(2x), inf-safe
            float th = fmaf(-2.f, __builtin_amdgcn_rcpf(e + 1.f), 1.f); // tanh(x)
            hsum = fmaf(th, Wc2[u], hsum);
        }
        const float chris = hsum + bc2v;  // lane holds chris for (pair=ph, k)

        // ricci first layer pre-activation for pairs (i,j0) and (i,j0+1)
        const float* mj0 = &mj[(b * M + j0) * 256 + l];
        const float* mj1 = mj0 + 256;
        float p00 = bmi[l]       + mj0[0];
        float p01 = bmi[l + 64]  + mj0[64];
        float p02 = bmi[l + 128] + mj0[128];
        float p03 = bmi[l + 192] + mj0[192];
        float p10 = bmi[l]       + mj1[0];
        float p11 = bmi[l + 64]  + mj1[64];
        float p12 = bmi[l + 128] + mj1[128];
        float p13 = bmi[l + 192] + mj1[192];
        #pragma unroll 8
        for (int kk = 0; kk < 32; ++kk) {
            const float c0 = __shfl(chris, kk);        // pair 0 chris_kk
            const float c1 = __shfl(chris, kk + 32);   // pair 1 chris_kk
            const float* wp = &wr1c[kk * 256 + l];
            const float w0 = wp[0], w1 = wp[64], w2 = wp[128], w3 = wp[192];
            p00 = fmaf(c0, w0, p00); p01 = fmaf(c0, w1, p01);
            p02 = fmaf(c0, w2, p02); p03 = fmaf(c0, w3, p03);
            p10 = fmaf(c1, w0, p10); p11 = fmaf(c1, w1, p11);
            p12 = fmaf(c1, w2, p12); p13 = fmaf(c1, w3, p13);
        }
        sacc0 += fmaxf(p00, 0.f) + fmaxf(p10, 0.f);
        sacc1 += fmaxf(p01, 0.f) + fmaxf(p11, 0.f);
        sacc2 += fmaxf(p02, 0.f) + fmaxf(p12, 0.f);
        sacc3 += fmaxf(p03, 0.f) + fmaxf(p13, 0.f);
    }
    atomicAdd(&Slds[l],       sacc0);
    atomicAdd(&Slds[l + 64],  sacc1);
    atomicAdd(&Slds[l + 128], sacc2);
    atomicAdd(&Slds[l + 192], sacc3);
    __syncthreads();
    atomicAdd(&S[b * 256 + t], Slds[t]);
}

// Kernel 4: ricci = sym((S/1024)@Wr2 + br2); flow; hamiltonian; output.
__global__ __launch_bounds__(256) void k_finish(
    const float* __restrict__ S, const float* __restrict__ Wr2,
    const float* __restrict__ br2, const float* __restrict__ points,
    const float* __restrict__ Wf1, const float* __restrict__ bf1,
    const float* __restrict__ Wf2, const float* __restrict__ bf2,
    const float* __restrict__ Wh1, const float* __restrict__ bh1,
    const float* __restrict__ Wh2, const float* __restrict__ bh2,
    float* __restrict__ out)
{
    const int b = blockIdx.x, t = threadIdx.x;
    __shared__ float s[256];
    __shared__ float P[M * M];
    __shared__ float ric[M * M];
    __shared__ float pl[M];
    __shared__ float fin[2 * M];
    __shared__ float hf[H];
    __shared__ float npos[M];
    __shared__ float hh[H];

    s[t] = S[b * 256 + t] * (1.f / 1024.f);
    if (t < M) pl[t] = points[b * M + t];
    __syncthreads();
    #pragma unroll
    for (int r = 0; r < 4; ++r) {
        const int d = t + 256 * r;
        float acc = br2[d];
        for (int u = 0; u < 256; ++u) acc = fmaf(s[u], Wr2[u * (M * M) + d], acc);
        P[d] = acc;
    }
    __syncthreads();
    #pragma unroll
    for (int r = 0; r < 4; ++r) {
        const int d = t + 256 * r;
        const int ii = d >> 5, jj = d & 31;
        ric[d] = 0.5f * (P[d] + P[jj * M + ii]);
    }
    __syncthreads();
    if (t < M) {
        float acc = 0.f;
        #pragma unroll
        for (int jj = 0; jj < M; ++jj) acc = fmaf(ric[t * M + jj], pl[jj], acc);
        fin[t] = pl[t];
        fin[M + t] = acc;
    }
    __syncthreads();
    if (t < H) {
        float acc = bf1[t];
        #pragma unroll
        for (int m = 0; m < 2 * M; ++m) acc = fmaf(fin[m], Wf1[m * H + t], acc);
        hf[t] = fmaxf(acc, 0.f);
    }
    __syncthreads();
    if (t < M) {
        float acc = bf2[t];
        #pragma unroll
        for (int u = 0; u < H; ++u) acc = fmaf(hf[u], Wf2[u * M + t], acc);
        npos[t] = pl[t] + acc;
    }
    __syncthreads();
    if (t < H) {
        float acc = bh1[t];
        #pragma unroll
        for (int m = 0; m < M; ++m) acc = fmaf(npos[m], Wh1[m * H + t], acc);
        hh[t] = tanhf(acc);
    }
    __syncthreads();
    if (t < 2 * M) {
        float acc = bh2[t];
        #pragma unroll
        for (int u = 0; u < H; ++u) acc = fmaf(hh[u], Wh2[u * (2 * M) + t], acc);
        out[b * (2 * M) + t] = acc;
    }
}

extern "C" void kernel_launch(void* const* d_in, const int* in_sizes, int n_in,
                              void* d_out, int out_size, void* d_ws, size_t ws_size,
                              hipStream_t stream)
{
    const float* points = (const float*)d_in[0];
    const float* Wm1 = (const float*)d_in[1];
    const float* bm1 = (const float*)d_in[2];
    const float* Wm2 = (const float*)d_in[3];
    const float* bm2 = (const float*)d_in[4];
    const float* Wc1 = (const float*)d_in[5];
    const float* bc1 = (const float*)d_in[6];
    const float* Wc2 = (const float*)d_in[7];
    const float* bc2 = (const float*)d_in[8];
    const float* Wr1 = (const float*)d_in[9];
    const float* br1 = (const float*)d_in[10];
    const float* Wr2 = (const float*)d_in[11];
    const float* br2 = (const float*)d_in[12];
    const float* Wf1 = (const float*)d_in[13];
    const float* bf1 = (const float*)d_in[14];
    const float* Wf2 = (const float*)d_in[15];
    const float* bf2 = (const float*)d_in[16];
    const float* Wh1 = (const float*)d_in[17];
    const float* bh1 = (const float*)d_in[18];
    const float* Wh2 = (const float*)d_in[19];
    const float* bh2 = (const float*)d_in[20];
    float* out = (float*)d_out;

    float* ws     = (float*)d_ws;
    float* metric = ws;                 // 32768
    float* mj     = ws + 32768;         // 262144
    float* S      = ws + 32768 + 262144; // 8192

    k_metric<<<B, 256, 0, stream>>>(points, Wm1, bm1, Wm2, bm2, metric, S);
    k_mj<<<B * M, 256, 0, stream>>>(metric, Wr1, mj);
    k_main<<<B * M, 256, 0, stream>>>(points, metric, Wc1, bc1, Wc2, bc2,
                                      Wr1, br1, mj, S);
    k_finish<<<B, 256, 0, stream>>>(S, Wr2, br2, points, Wf1, bf1, Wf2, bf2,
                                    Wh1, bh1, Wh2, bh2, out);
}

// Round 3
// 89.357 us; speedup vs baseline: 1.1930x; 1.1930x over previous
//
#include <hip/hip_runtime.h>

#define B 32
#define M 32
#define H 128
#define EPS 1e-6f
#define TSCALE 2.8853900817779268f   // 2*log2(e)

// ---------------- workspace layout (floats) ----------------
// metric @ 0      : 32768
// mj     @ 32768  : 262144   mj[b][j][d] = metric[b,j,:] @ Wr1[64:96]
// S      @ 294912 : 8192
// bc1s   @ 303104 : 128      bc1 * 2log2(e)
// Kc     @ 303232 : 1        sum(Wc2) + bc2

#define FMA4(P, s, W) \
    P.x = fmaf((s), (W).x, P.x); P.y = fmaf((s), (W).y, P.y); \
    P.z = fmaf((s), (W).z, P.z); P.w = fmaf((s), (W).w, P.w);

// Kernel 1: metric + mj + zero S + scaled christoffel constants.
__global__ __launch_bounds__(256) void k_prep(
    const float* __restrict__ points, const float* __restrict__ Wm1,
    const float* __restrict__ bm1, const float* __restrict__ Wm2,
    const float* __restrict__ bm2, const float* __restrict__ Wr1,
    const float* __restrict__ bc1, const float* __restrict__ Wc2,
    const float* __restrict__ bc2,
    float* __restrict__ metric, float* __restrict__ mj,
    float* __restrict__ S, float* __restrict__ bc1s, float* __restrict__ Kc)
{
    const int b = blockIdx.x, t = threadIdx.x;
    __shared__ float p[M];
    __shared__ float h[H];
    __shared__ float comps[M * M];
    __shared__ float msym[M * M];
    if (t < M) p[t] = points[b * M + t];
    __syncthreads();
    if (t < H) {
        float acc = bm1[t];
        #pragma unroll
        for (int m = 0; m < M; ++m) acc = fmaf(p[m], Wm1[m * H + t], acc);
        h[t] = fmaxf(acc, 0.f);
    }
    __syncthreads();
    #pragma unroll
    for (int r = 0; r < 4; ++r) {
        const int d = t + 256 * r;
        float acc = bm2[d];
        for (int u = 0; u < H; ++u) acc = fmaf(h[u], Wm2[u * (M * M) + d], acc);
        comps[d] = acc;
    }
    __syncthreads();
    #pragma unroll
    for (int r = 0; r < 4; ++r) {
        const int d = t + 256 * r;
        const int ii = d >> 5, jj = d & 31;
        float v = 0.5f * (comps[ii * M + jj] + comps[jj * M + ii]) + (ii == jj ? EPS : 0.f);
        metric[b * M * M + d] = v;
        msym[d] = v;
    }
    S[b * 256 + t] = 0.f;
    __syncthreads();
    // mj[b][x][t]: weight column cached in registers, reused across all x
    float wreg[M];
    #pragma unroll
    for (int m = 0; m < M; ++m) wreg[m] = Wr1[(64 + m) * 256 + t];
    const float4* msym4 = (const float4*)msym;
    for (int x = 0; x < M; ++x) {
        float acc = 0.f;
        #pragma unroll
        for (int mq = 0; mq < 8; ++mq) {
            float4 mv = msym4[x * 8 + mq];
            acc = fmaf(mv.x, wreg[4 * mq + 0], acc);
            acc = fmaf(mv.y, wreg[4 * mq + 1], acc);
            acc = fmaf(mv.z, wreg[4 * mq + 2], acc);
            acc = fmaf(mv.w, wreg[4 * mq + 3], acc);
        }
        mj[(b * M + x) * 256 + t] = acc;
    }
    if (b == 0) {
        if (t < H) bc1s[t] = bc1[t] * TSCALE;
        if (t == 0) {
            float s = bc2[0];
            for (int u = 0; u < H; ++u) s += Wc2[u];
            Kc[0] = s;
        }
    }
}

// Kernel 2 (dominant): per block (b,i): christoffel MLP for all (j,k) +
// ricci layer-1 + relu + reduce into S[b]. 512 threads = 8 waves, wave w
// owns j in {2w, 2w+1, 16+2w, 16+2w+1}.
__global__ __launch_bounds__(512, 6) void k_main2(
    const float* __restrict__ points, const float* __restrict__ metric,
    const float* __restrict__ mj, const float* __restrict__ Wc1,
    const float* __restrict__ Wc2, const float* __restrict__ bc1s,
    const float* __restrict__ Kc, const float* __restrict__ Wr1,
    const float* __restrict__ br1, float* __restrict__ S)
{
    const int blk = blockIdx.x;
    const int b = blk >> 5, i = blk & 31;
    const int t = threadIdx.x;

    __shared__ float wr1c[M * 256];   // Wr1[96:128] — 32 KB
    __shared__ float mlds[M * M];     // 4 KB
    __shared__ float bmi[256];
    __shared__ float chlds[8 * 128];  // per-wave chris scratch
    __shared__ float Slds[256];

    {
        const float4* src = (const float4*)(Wr1 + 96 * 256);
        float4* dst = (float4*)wr1c;
        #pragma unroll
        for (int r = 0; r < 4; ++r) dst[t + 512 * r] = src[t + 512 * r];
    }
    mlds[t] = metric[b * 1024 + t];
    mlds[t + 512] = metric[b * 1024 + t + 512];
    if (t < 256) Slds[t] = 0.f;
    __syncthreads();

    if (t < 256) {
        float acc = br1[t];
        #pragma unroll
        for (int m = 0; m < M; ++m) acc = fmaf(points[b * M + m], Wr1[m * 256 + t], acc);
        #pragma unroll
        for (int m = 0; m < M; ++m) acc = fmaf(mlds[i * M + m], Wr1[(32 + m) * 256 + t], acc);
        bmi[t] = acc;
    }

    const int w = t >> 6, l = t & 63;
    const int ph = l >> 5, k = l & 31;
    const float gki_s = mlds[i * M + k] * TSCALE;  // metric symmetric: g[k][i]==g[i][k]
    const float KcV = Kc[0];

    // --- christoffel phase: each lane one (j,k) triple per iteration ---
    #pragma unroll
    for (int it = 0; it < 2; ++it) {
        const int j = it * 16 + w * 2 + ph;
        const float gij_s = mlds[i * M + j] * TSCALE;
        const float gjk_s = mlds[j * M + k] * TSCALE;
        float h0 = 0.f, h1 = 0.f, h2 = 0.f, h3 = 0.f;
        #pragma unroll 2
        for (int u = 0; u < H; u += 4) {
            float pa = fmaf(gij_s, Wc1[u+0], fmaf(gjk_s, Wc1[H+u+0], fmaf(gki_s, Wc1[2*H+u+0], bc1s[u+0])));
            float pb = fmaf(gij_s, Wc1[u+1], fmaf(gjk_s, Wc1[H+u+1], fmaf(gki_s, Wc1[2*H+u+1], bc1s[u+1])));
            float pc = fmaf(gij_s, Wc1[u+2], fmaf(gjk_s, Wc1[H+u+2], fmaf(gki_s, Wc1[2*H+u+2], bc1s[u+2])));
            float pd = fmaf(gij_s, Wc1[u+3], fmaf(gjk_s, Wc1[H+u+3], fmaf(gki_s, Wc1[2*H+u+3], bc1s[u+3])));
            h0 = fmaf(__builtin_amdgcn_rcpf(__builtin_amdgcn_exp2f(pa) + 1.f), Wc2[u+0], h0);
            h1 = fmaf(__builtin_amdgcn_rcpf(__builtin_amdgcn_exp2f(pb) + 1.f), Wc2[u+1], h1);
            h2 = fmaf(__builtin_amdgcn_rcpf(__builtin_amdgcn_exp2f(pc) + 1.f), Wc2[u+2], h2);
            h3 = fmaf(__builtin_amdgcn_rcpf(__builtin_amdgcn_exp2f(pd) + 1.f), Wc2[u+3], h3);
        }
        // tanh folded: chris = Kc - 2 * sum(rcp * Wc2)
        chlds[w * 128 + it * 64 + l] = fmaf(-2.f, (h0 + h1) + (h2 + h3), KcV);
    }
    __syncthreads();   // bmi + chlds ready

    // --- ricci phase: lane l owns dims 4l..4l+3 for the wave's 4 j's ---
    const float4* mj4 = (const float4*)(mj + b * M * 256);
    const float4* wr1c4 = (const float4*)wr1c;
    const float* chw = chlds + w * 128;
    float4 bmiv = ((const float4*)bmi)[l];
    const int jb = w * 2;
    float4 p00 = mj4[(jb + 0) * 64 + l];
    float4 p01 = mj4[(jb + 1) * 64 + l];
    float4 p10 = mj4[(jb + 16) * 64 + l];
    float4 p11 = mj4[(jb + 17) * 64 + l];
    p00.x += bmiv.x; p00.y += bmiv.y; p00.z += bmiv.z; p00.w += bmiv.w;
    p01.x += bmiv.x; p01.y += bmiv.y; p01.z += bmiv.z; p01.w += bmiv.w;
    p10.x += bmiv.x; p10.y += bmiv.y; p10.z += bmiv.z; p10.w += bmiv.w;
    p11.x += bmiv.x; p11.y += bmiv.y; p11.z += bmiv.z; p11.w += bmiv.w;

    #define STEP(W, kk) { \
        float s0 = chw[(kk)];      float s1 = chw[32 + (kk)]; \
        float s2 = chw[64 + (kk)]; float s3 = chw[96 + (kk)]; \
        FMA4(p00, s0, W); FMA4(p01, s1, W); FMA4(p10, s2, W); FMA4(p11, s3, W); }

    #pragma unroll
    for (int kc = 0; kc < 4; ++kc) {
        const int kb = kc * 8;
        float4 w0 = wr1c4[(kb + 0) * 64 + l];
        float4 w1 = wr1c4[(kb + 1) * 64 + l];
        float4 w2 = wr1c4[(kb + 2) * 64 + l];
        float4 w3 = wr1c4[(kb + 3) * 64 + l];
        float4 w4 = wr1c4[(kb + 4) * 64 + l];
        float4 w5 = wr1c4[(kb + 5) * 64 + l];
        float4 w6 = wr1c4[(kb + 6) * 64 + l];
        float4 w7 = wr1c4[(kb + 7) * 64 + l];
        STEP(w0, kb + 0) STEP(w1, kb + 1) STEP(w2, kb + 2) STEP(w3, kb + 3)
        STEP(w4, kb + 4) STEP(w5, kb + 5) STEP(w6, kb + 6) STEP(w7, kb + 7)
    }
    #undef STEP

    float r0 = fmaxf(p00.x,0.f)+fmaxf(p01.x,0.f)+fmaxf(p10.x,0.f)+fmaxf(p11.x,0.f);
    float r1 = fmaxf(p00.y,0.f)+fmaxf(p01.y,0.f)+fmaxf(p10.y,0.f)+fmaxf(p11.y,0.f);
    float r2 = fmaxf(p00.z,0.f)+fmaxf(p01.z,0.f)+fmaxf(p10.z,0.f)+fmaxf(p11.z,0.f);
    float r3 = fmaxf(p00.w,0.f)+fmaxf(p01.w,0.f)+fmaxf(p10.w,0.f)+fmaxf(p11.w,0.f);
    atomicAdd(&Slds[4*l + 0], r0);
    atomicAdd(&Slds[4*l + 1], r1);
    atomicAdd(&Slds[4*l + 2], r2);
    atomicAdd(&Slds[4*l + 3], r3);
    __syncthreads();
    if (t < 256) atomicAdd(&S[b * 256 + t], Slds[t]);
}

// Kernel 3: ricci = sym((S/1024)@Wr2 + br2); flow; hamiltonian; output.
__global__ __launch_bounds__(256) void k_finish(
    const float* __restrict__ S, const float* __restrict__ Wr2,
    const float* __restrict__ br2, const float* __restrict__ points,
    const float* __restrict__ Wf1, const float* __restrict__ bf1,
    const float* __restrict__ Wf2, const float* __restrict__ bf2,
    const float* __restrict__ Wh1, const float* __restrict__ bh1,
    const float* __restrict__ Wh2, const float* __restrict__ bh2,
    float* __restrict__ out)
{
    const int b = blockIdx.x, t = threadIdx.x;
    __shared__ float s[256];
    __shared__ float P[M * M];
    __shared__ float ric[M * M];
    __shared__ float pl[M];
    __shared__ float fin[2 * M];
    __shared__ float hf[H];
    __shared__ float npos[M];
    __shared__ float hh[H];

    s[t] = S[b * 256 + t] * (1.f / 1024.f);
    if (t < M) pl[t] = points[b * M + t];
    __syncthreads();
    #pragma unroll
    for (int r = 0; r < 4; ++r) {
        const int d = t + 256 * r;
        float acc = br2[d];
        for (int u = 0; u < 256; ++u) acc = fmaf(s[u], Wr2[u * (M * M) + d], acc);
        P[d] = acc;
    }
    __syncthreads();
    #pragma unroll
    for (int r = 0; r < 4; ++r) {
        const int d = t + 256 * r;
        const int ii = d >> 5, jj = d & 31;
        ric[d] = 0.5f * (P[d] + P[jj * M + ii]);
    }
    __syncthreads();
    if (t < M) {
        float acc = 0.f;
        #pragma unroll
        for (int jj = 0; jj < M; ++jj) acc = fmaf(ric[t * M + jj], pl[jj], acc);
        fin[t] = pl[t];
        fin[M + t] = acc;
    }
    __syncthreads();
    if (t < H) {
        float acc = bf1[t];
        #pragma unroll
        for (int m = 0; m < 2 * M; ++m) acc = fmaf(fin[m], Wf1[m * H + t], acc);
        hf[t] = fmaxf(acc, 0.f);
    }
    __syncthreads();
    if (t < M) {
        float acc = bf2[t];
        #pragma unroll
        for (int u = 0; u < H; ++u) acc = fmaf(hf[u], Wf2[u * M + t], acc);
        npos[t] = pl[t] + acc;
    }
    __syncthreads();
    if (t < H) {
        float acc = bh1[t];
        #pragma unroll
        for (int m = 0; m < M; ++m) acc = fmaf(npos[m], Wh1[m * H + t], acc);
        hh[t] = tanhf(acc);
    }
    __syncthreads();
    if (t < 2 * M) {
        float acc = bh2[t];
        #pragma unroll
        for (int u = 0; u < H; ++u) acc = fmaf(hh[u], Wh2[u * (2 * M) + t], acc);
        out[b * (2 * M) + t] = acc;
    }
}

extern "C" void kernel_launch(void* const* d_in, const int* in_sizes, int n_in,
                              void* d_out, int out_size, void* d_ws, size_t ws_size,
                              hipStream_t stream)
{
    const float* points = (const float*)d_in[0];
    const float* Wm1 = (const float*)d_in[1];
    const float* bm1 = (const float*)d_in[2];
    const float* Wm2 = (const float*)d_in[3];
    const float* bm2 = (const float*)d_in[4];
    const float* Wc1 = (const float*)d_in[5];
    const float* bc1 = (const float*)d_in[6];
    const float* Wc2 = (const float*)d_in[7];
    const float* bc2 = (const float*)d_in[8];
    const float* Wr1 = (const float*)d_in[9];
    const float* br1 = (const float*)d_in[10];
    const float* Wr2 = (const float*)d_in[11];
    const float* br2 = (const float*)d_in[12];
    const float* Wf1 = (const float*)d_in[13];
    const float* bf1 = (const float*)d_in[14];
    const float* Wf2 = (const float*)d_in[15];
    const float* bf2 = (const float*)d_in[16];
    const float* Wh1 = (const float*)d_in[17];
    const float* bh1 = (const float*)d_in[18];
    const float* Wh2 = (const float*)d_in[19];
    const float* bh2 = (const float*)d_in[20];
    float* out = (float*)d_out;

    float* ws     = (float*)d_ws;
    float* metric = ws;                    // 32768
    float* mj     = ws + 32768;            // 262144
    float* S      = ws + 294912;           // 8192
    float* bc1s   = ws + 303104;           // 128
    float* Kc     = ws + 303232;           // 1

    k_prep<<<B, 256, 0, stream>>>(points, Wm1, bm1, Wm2, bm2, Wr1, bc1, Wc2, bc2,
                                  metric, mj, S, bc1s, Kc);
    k_main2<<<B * M, 512, 0, stream>>>(points, metric, mj, Wc1, Wc2, bc1s, Kc,
                                       Wr1, br1, S);
    k_finish<<<B, 256, 0, stream>>>(S, Wr2, br2, points, Wf1, bf1, Wf2, bf2,
                                    Wh1, bh1, Wh2, bh2, out);
}